// Round 6
// baseline (21.998 us; speedup 1.0000x reference)
//
#include <hip/hip_runtime.h>

typedef __attribute__((ext_vector_type(4))) float float4v;

#define LSTR 396            // LDS row stride in floats (384+12; 12 mod 32 spreads banks)
#define LBUF (48 * LSTR)    // floats per buffer (3 channels x 16 rows) = 19008

// out[b, t, d], B=32, T=577, D=768 (f32).
// t==0: cls[b,:] + pos[0,:].
// t>=1: q=t-1, hp=q/24, wp=q%24; d=c*256+i*16+jj -> img[b,c,hp*16+i,wp*16+jj].
//
// Block = (b, hp-triple). Unit = one patch-row (b,hp):
//   read  3 x 24.6KB contiguous img slabs (c=0,1,2) -> LDS (transpose),
//   write 24 tokens x 3072B = 73.7KB fully contiguous out run (+pos, same layout).
// Grid 256 = exactly 1 block/CU (152KB LDS), 3 units/block, reg-prefetch dbuf.
__global__ __launch_bounds__(1024) void patch_embed_kernel(
    const float* __restrict__ img, const float* __restrict__ cls,
    const float* __restrict__ pos, float* __restrict__ out)
{
    __shared__ __align__(16) float lds[2][LBUF];
    const int tid = threadIdx.x;
    const int bid = blockIdx.x;
    const int b   = bid >> 3;          // image 0..31
    const int hp0 = (bid & 7) * 3;     // first patch-row of this block's triple

    // cls tokens (blocks 0..5): 32*768 floats = 6144 float4, 1 per thread.
    if (bid < 6) {
        int idx = bid * 1024 + tid;
        int cb  = idx / 192;
        int d4  = idx - cb * 192;
        float4v v = *(const float4v*)(cls + (size_t)cb * 768 + (size_t)d4 * 4);
        float4v p = *(const float4v*)(pos + (size_t)d4 * 4);
        *(float4v*)(out + ((size_t)cb * 577) * 768 + (size_t)d4 * 4) = v + p;
    }

    // 4608 float4s per unit; threads tid<512 handle 5, others 4 (wave-uniform).
    auto load_regs = [&](int hp, float4v* r) {
        #pragma unroll
        for (int j = 0; j < 5; ++j) {
            int fi = tid + j * 1024;
            if (fi < 4608) {
                int c  = fi / 1536;            // channel slab
                int r2 = fi - c * 1536;        // f4 within slab (contiguous)
                r[j] = *(const float4v*)(
                    img + (((size_t)(b * 3 + c) * 384) + hp * 16) * 384
                        + (size_t)r2 * 4);
            }
        }
    };
    auto regs_to_lds = [&](float4v* r, int buf) {
        float* L = lds[buf];
        #pragma unroll
        for (int j = 0; j < 5; ++j) {
            int fi = tid + j * 1024;
            if (fi < 4608) {
                int c  = fi / 1536;
                int r2 = fi - c * 1536;
                int i  = r2 / 96;              // img row within slab
                int wq = r2 - i * 96;          // f4 within row
                *(float4v*)(L + (c * 16 + i) * LSTR + wq * 4) = r[j];
            }
        }
    };
    auto store_unit = [&](int hp, int buf) {
        const float* L = lds[buf];
        const float* pbase = pos + (size_t)(1 + hp * 24) * 768;
        float*       obase = out + ((size_t)b * 577 + 1 + hp * 24) * 768;
        #pragma unroll
        for (int j = 0; j < 5; ++j) {
            int o4 = tid + j * 1024;
            if (o4 < 4608) {
                int wp = o4 / 192;             // token within patch-row
                int d4 = o4 - wp * 192;        // f4 within 768-float token
                int c  = d4 >> 6;
                int i  = (d4 >> 2) & 15;
                int j4 = d4 & 3;
                float4v v = *(const float4v*)(
                    L + (c * 16 + i) * LSTR + wp * 16 + j4 * 4);
                float4v p = *(const float4v*)(pbase + (size_t)o4 * 4);
                *(float4v*)(obase + (size_t)o4 * 4) = v + p;
            }
        }
    };

    float4v r[5];
    load_regs(hp0, r);
    regs_to_lds(r, 0);
    __syncthreads();

    load_regs(hp0 + 1, r);          // prefetch issues before store consumes buf0
    store_unit(hp0, 0);
    regs_to_lds(r, 1);
    __syncthreads();

    load_regs(hp0 + 2, r);
    store_unit(hp0 + 1, 1);
    regs_to_lds(r, 0);
    __syncthreads();

    store_unit(hp0 + 2, 0);
}

extern "C" void kernel_launch(void* const* d_in, const int* in_sizes, int n_in,
                              void* d_out, int out_size, void* d_ws, size_t ws_size,
                              hipStream_t stream) {
    const float* img = (const float*)d_in[0];   // [32,3,384,384] f32
    const float* cls = (const float*)d_in[1];   // [32,768]       f32
    const float* pos = (const float*)d_in[2];   // [577,768]      f32
    float* out = (float*)d_out;                 // [32,577,768]   f32

    patch_embed_kernel<<<256, 1024, 0, stream>>>(img, cls, pos, out);
}